// Round 14
// baseline (1471.207 us; speedup 1.0000x reference)
//
#include <hip/hip_runtime.h>

// ---------------------------------------------------------------------------
// BN -> patchify -> embed -> all-pairs MLP_LN (correl, U[i]+V[j] split) ->
// xcorr pyramid -> interleave -> appc -> xpath pyramid -> 4-layer head.
// All fp32.  E=100, HID=150, P=256, B=4.
//
// v17 = v11 (R10) hot kernels byte-identical + single-wave tail kernel:
// 64 threads, 4 rows/block, LDS-broadcast weights (v5 cadence, J=1).
// Used for nrows <= 4096 (xcorr tail, appc, xpath). Rationale: per-WAVE
// weight-read cost is fixed (~918 ds_read/level); single-wave blocks at
// <=4 waves/CU cut per-level wall from ~30-45us to ~5-18us.
// ---------------------------------------------------------------------------

#define RR 64          // rows per block (big kernels)
#define HT_S 156       // ht row stride (156%32=28 -> 8 start banks, 2-way free)
#define W1_S 44        // w1 slab row stride (40-K chunks)
#define W2_S 76        // w2 slab row stride (76-K halves)
#define WBUF_FLOATS 7600   // max(150*44=6600, 100*76=7600)

// ---- FMA helpers: compile-time k4, broadcast w from LDS slab ----
__device__ __forceinline__ void fma10(float (&acc)[10][4], const float* __restrict__ wbuf,
                                      const int* woff, int k4,
                                      float4 x0, float4 x1, float4 x2, float4 x3)
{
#pragma unroll
  for (int i = 0; i < 10; ++i) {
    float4 w = *reinterpret_cast<const float4*>(&wbuf[woff[i] + 4 * k4]);
    acc[i][0] += x0.x * w.x; acc[i][0] += x0.y * w.y; acc[i][0] += x0.z * w.z; acc[i][0] += x0.w * w.w;
    acc[i][1] += x1.x * w.x; acc[i][1] += x1.y * w.y; acc[i][1] += x1.z * w.z; acc[i][1] += x1.w * w.w;
    acc[i][2] += x2.x * w.x; acc[i][2] += x2.y * w.y; acc[i][2] += x2.z * w.z; acc[i][2] += x2.w * w.w;
    acc[i][3] += x3.x * w.x; acc[i][3] += x3.y * w.y; acc[i][3] += x3.z * w.z; acc[i][3] += x3.w * w.w;
  }
}
__device__ __forceinline__ void fma7(float (&acc)[7][4], const float* __restrict__ wbuf,
                                     const int* woff, int k4,
                                     float4 x0, float4 x1, float4 x2, float4 x3)
{
#pragma unroll
  for (int i = 0; i < 7; ++i) {
    float4 w = *reinterpret_cast<const float4*>(&wbuf[woff[i] + 4 * k4]);
    acc[i][0] += x0.x * w.x; acc[i][0] += x0.y * w.y; acc[i][0] += x0.z * w.z; acc[i][0] += x0.w * w.w;
    acc[i][1] += x1.x * w.x; acc[i][1] += x1.y * w.y; acc[i][1] += x1.z * w.z; acc[i][1] += x1.w * w.w;
    acc[i][2] += x2.x * w.x; acc[i][2] += x2.y * w.y; acc[i][2] += x2.z * w.z; acc[i][2] += x2.w * w.w;
    acc[i][3] += x3.x * w.x; acc[i][3] += x3.y * w.y; acc[i][3] += x3.z * w.z; acc[i][3] += x3.w * w.w;
  }
}

// ---- LayerNorm epilogue over acc[7][4] ----
__device__ __forceinline__ void ln_store(
    float acc[7][4], int a, int b, int vrows,
    const float* __restrict__ b2, const float* __restrict__ gg,
    const float* __restrict__ bb, float* __restrict__ out, long row0)
{
  float s[4] = {0.f, 0.f, 0.f, 0.f};
#pragma unroll
  for (int i = 0; i < 7; ++i) {
    int e = a + 16 * i;
    if (e < 100) {
      float bv = b2[e];
#pragma unroll
      for (int j = 0; j < 4; ++j) { acc[i][j] += bv; s[j] += acc[i][j]; }
    }
  }
#pragma unroll
  for (int m = 8; m; m >>= 1)
#pragma unroll
    for (int j = 0; j < 4; ++j) s[j] += __shfl_xor(s[j], m, 16);
  float mu[4], vv[4] = {0.f, 0.f, 0.f, 0.f};
#pragma unroll
  for (int j = 0; j < 4; ++j) mu[j] = s[j] * 0.01f;
#pragma unroll
  for (int i = 0; i < 7; ++i) {
    int e = a + 16 * i;
    if (e < 100) {
#pragma unroll
      for (int j = 0; j < 4; ++j) { float d = acc[i][j] - mu[j]; vv[j] += d * d; }
    }
  }
#pragma unroll
  for (int m = 8; m; m >>= 1)
#pragma unroll
    for (int j = 0; j < 4; ++j) vv[j] += __shfl_xor(vv[j], m, 16);
  float rs[4];
#pragma unroll
  for (int j = 0; j < 4; ++j) rs[j] = rsqrtf(vv[j] * 0.01f + 1e-5f);
#pragma unroll
  for (int j = 0; j < 4; ++j) {
    int r = b + 16 * j;
    if (r < vrows) {
      float* o = out + (row0 + r) * 100;
#pragma unroll
      for (int i = 0; i < 7; ++i) {
        int e = a + 16 * i;
        if (e < 100) o[e] = (acc[i][j] - mu[j]) * rs[j] * gg[e] + bb[e];
      }
    }
  }
}

// ---- phase 2: (64 x 152) @ w2^T + b2 -> LN -> store; hv ping-pong ----
__device__ __forceinline__ void phase2_ln(
    float* __restrict__ wbuf, const float* __restrict__ ht, int vrows,
    const float* __restrict__ w2, const float* __restrict__ b2,
    const float* __restrict__ gg, const float* __restrict__ bb,
    float* __restrict__ out, long row0)
{
  const int tid = threadIdx.x;
  const int a = tid & 15;
  const int b = tid >> 4;
  float acc[7][4];
#pragma unroll
  for (int i = 0; i < 7; ++i)
#pragma unroll
    for (int j = 0; j < 4; ++j) acc[i][j] = 0.f;
  int woff[7];
#pragma unroll
  for (int i = 0; i < 7; ++i) { int e = a + 16 * i; woff[i] = (e < 100 ? e : 0) * W2_S; }
  const float* h0 = ht + b * HT_S;
  const float* h1 = ht + (b + 16) * HT_S;
  const float* h2 = ht + (b + 32) * HT_S;
  const float* h3 = ht + (b + 48) * HT_S;

  for (int h = 0; h < 2; ++h) {
    __syncthreads();                      // wbuf free / ht ready
    for (int idx = tid; idx < 3800; idx += 256) {   // 100 rows x 38 float2
      int r = idx / 38, c = idx - r * 38;
      int k = 76 * h + 2 * c;
      float2 v;
      if (k < 150) v = *reinterpret_cast<const float2*>(w2 + r * 150 + k);
      else         v = make_float2(0.f, 0.f);
      *reinterpret_cast<float2*>(&wbuf[r * W2_S + 2 * c]) = v;
    }
    __syncthreads();                      // wbuf ready
    const int kb = 76 * h;
    float4 xa0 = *reinterpret_cast<const float4*>(h0 + kb);
    float4 xa1 = *reinterpret_cast<const float4*>(h1 + kb);
    float4 xa2 = *reinterpret_cast<const float4*>(h2 + kb);
    float4 xa3 = *reinterpret_cast<const float4*>(h3 + kb);
#pragma unroll
    for (int p = 0; p < 9; ++p) {
      const int ke = kb + 4 * (2 * p + 1);
      float4 xb0 = *reinterpret_cast<const float4*>(h0 + ke);
      float4 xb1 = *reinterpret_cast<const float4*>(h1 + ke);
      float4 xb2 = *reinterpret_cast<const float4*>(h2 + ke);
      float4 xb3 = *reinterpret_cast<const float4*>(h3 + ke);
      fma7(acc, wbuf, woff, 2 * p, xa0, xa1, xa2, xa3);
      const int kf = kb + 4 * (2 * p + 2);            // p=8 -> k4=18 (cols 150/151 zero)
      xa0 = *reinterpret_cast<const float4*>(h0 + kf);
      xa1 = *reinterpret_cast<const float4*>(h1 + kf);
      xa2 = *reinterpret_cast<const float4*>(h2 + kf);
      xa3 = *reinterpret_cast<const float4*>(h3 + kf);
      fma7(acc, wbuf, woff, 2 * p + 1, xb0, xb1, xb2, xb3);
    }
    fma7(acc, wbuf, woff, 18, xa0, xa1, xa2, xa3);    // tail k4=18
  }
  ln_store(acc, a, b, vrows, b2, gg, bb, out, row0);
}

// ---- generic merge: rows of 200 -> Linear(150)+ReLU -> Linear(100) -> LN ----
__global__ __launch_bounds__(256, 2) void mlp_merge_kernel(
    const float* __restrict__ in, float* __restrict__ out,
    const float* __restrict__ w1, const float* __restrict__ b1,
    const float* __restrict__ w2, const float* __restrict__ b2,
    const float* __restrict__ gg, const float* __restrict__ bb,
    int nrows)
{
  __shared__ __align__(16) float wbuf[WBUF_FLOATS];   // 30.4 KB
  __shared__ __align__(16) float ht[RR * HT_S];       // 39.9 KB
  const int tid = threadIdx.x;
  const int a = tid & 15;
  const int b = tid >> 4;
  const long row0 = (long)blockIdx.x * RR;
  const int vrows = min(RR, (int)(nrows - row0));
  const float* xr0 = in + (row0 + (b < vrows ? b : 0)) * 200;
  const float* xr1 = in + (row0 + (b + 16 < vrows ? b + 16 : 0)) * 200;
  const float* xr2 = in + (row0 + (b + 32 < vrows ? b + 32 : 0)) * 200;
  const float* xr3 = in + (row0 + (b + 48 < vrows ? b + 48 : 0)) * 200;
  int woff[10];
#pragma unroll
  for (int i = 0; i < 10; ++i) { int t = a + 16 * i; woff[i] = (t < 150 ? t : 0) * W1_S; }
  float acc[10][4];
#pragma unroll
  for (int i = 0; i < 10; ++i)
#pragma unroll
    for (int j = 0; j < 4; ++j) acc[i][j] = 0.f;

  // phase 1: K=200 in 5 chunks of 40 (10 k4 each), x ping-pong
  for (int c = 0; c < 5; ++c) {
    const int k0 = 40 * c;
    __syncthreads();                      // wbuf free
    for (int idx = tid; idx < 1500; idx += 256) {     // 150 rows x 10 float4
      int r = idx / 10, c4 = idx - r * 10;
      *reinterpret_cast<float4*>(&wbuf[r * W1_S + 4 * c4]) =
          *reinterpret_cast<const float4*>(w1 + r * 200 + k0 + 4 * c4);
    }
    __syncthreads();                      // wbuf ready
    float4 xa0 = *reinterpret_cast<const float4*>(xr0 + k0);
    float4 xa1 = *reinterpret_cast<const float4*>(xr1 + k0);
    float4 xa2 = *reinterpret_cast<const float4*>(xr2 + k0);
    float4 xa3 = *reinterpret_cast<const float4*>(xr3 + k0);
#pragma unroll
    for (int p = 0; p < 5; ++p) {
      const int ke = k0 + 4 * (2 * p + 1);
      float4 xb0 = *reinterpret_cast<const float4*>(xr0 + ke);
      float4 xb1 = *reinterpret_cast<const float4*>(xr1 + ke);
      float4 xb2 = *reinterpret_cast<const float4*>(xr2 + ke);
      float4 xb3 = *reinterpret_cast<const float4*>(xr3 + ke);
      fma10(acc, wbuf, woff, 2 * p, xa0, xa1, xa2, xa3);
      if (p < 4) {
        const int kf = k0 + 4 * (2 * p + 2);
        xa0 = *reinterpret_cast<const float4*>(xr0 + kf);
        xa1 = *reinterpret_cast<const float4*>(xr1 + kf);
        xa2 = *reinterpret_cast<const float4*>(xr2 + kf);
        xa3 = *reinterpret_cast<const float4*>(xr3 + kf);
      }
      fma10(acc, wbuf, woff, 2 * p + 1, xb0, xb1, xb2, xb3);
    }
  }
  // ReLU + bias -> ht; zero pad cols 150..155
#pragma unroll
  for (int i = 0; i < 10; ++i) {
    int t = a + 16 * i;
    if (t < 150) {
      float bt = b1[t];
      ht[b * HT_S + t] = fmaxf(acc[0][0] * 0.f + acc[i][0] + bt, 0.f);
      ht[(b + 16) * HT_S + t] = fmaxf(acc[i][1] + bt, 0.f);
      ht[(b + 32) * HT_S + t] = fmaxf(acc[i][2] + bt, 0.f);
      ht[(b + 48) * HT_S + t] = fmaxf(acc[i][3] + bt, 0.f);
    } else if (t < 156) {
      ht[b * HT_S + t] = 0.f;
      ht[(b + 16) * HT_S + t] = 0.f;
      ht[(b + 32) * HT_S + t] = 0.f;
      ht[(b + 48) * HT_S + t] = 0.f;
    }
  }
  phase2_ln(wbuf, ht, vrows, w2, b2, gg, bb, out, row0);
}

// ---- single-wave tail merge: 64 threads, 4 rows/block, LDS-broadcast w ----
// For nrows <= 4096: <=4 waves/CU -> per-level wall ~5-18us instead of 30-45.
__global__ __launch_bounds__(64) void mlp_merge_wave_kernel(
    const float* __restrict__ in, float* __restrict__ out,
    const float* __restrict__ w1, const float* __restrict__ b1,
    const float* __restrict__ w2, const float* __restrict__ b2,
    const float* __restrict__ gg, const float* __restrict__ bb,
    int nrows)
{
  __shared__ __align__(16) float wbuf[WBUF_FLOATS];   // 30.4 KB
  __shared__ __align__(16) float ht[4 * HT_S];        // 2.5 KB
  const int tid = threadIdx.x;           // 0..63
  const int a = tid & 15;
  const int b = tid >> 4;                // 0..3
  const long row0 = (long)blockIdx.x * 4;
  const int vrows = min(4, (int)(nrows - row0));
  const float* xrow = in + (row0 + (b < vrows ? b : 0)) * 200;

  int woff[10];
#pragma unroll
  for (int i = 0; i < 10; ++i) { int t = a + 16 * i; woff[i] = (t < 150 ? t : 0) * W1_S; }
  float acc[10];
#pragma unroll
  for (int i = 0; i < 10; ++i) acc[i] = 0.f;

  // phase 1: K=200 in 5 chunks of 40
  for (int c = 0; c < 5; ++c) {
    const int k0 = 40 * c;
    __syncthreads();
    for (int idx = tid; idx < 1500; idx += 64) {      // 150 rows x 10 float4
      int r = idx / 10, c4 = idx - r * 10;
      *reinterpret_cast<float4*>(&wbuf[r * W1_S + 4 * c4]) =
          *reinterpret_cast<const float4*>(w1 + r * 200 + k0 + 4 * c4);
    }
    __syncthreads();
#pragma unroll
    for (int k4 = 0; k4 < 10; ++k4) {
      float4 x = *reinterpret_cast<const float4*>(xrow + k0 + 4 * k4);
#pragma unroll
      for (int i = 0; i < 10; ++i) {
        float4 w = *reinterpret_cast<const float4*>(&wbuf[woff[i] + 4 * k4]);
        acc[i] += x.x * w.x; acc[i] += x.y * w.y;
        acc[i] += x.z * w.z; acc[i] += x.w * w.w;
      }
    }
  }
  // ReLU + bias -> ht; zero cols 150/151
#pragma unroll
  for (int i = 0; i < 10; ++i) {
    int t = a + 16 * i;
    if (t < 150) ht[b * HT_S + t] = fmaxf(acc[i] + b1[t], 0.f);
  }
  if (tid < 8) ht[(tid >> 1) * HT_S + 150 + (tid & 1)] = 0.f;

  // phase 2: K=152 in 2 halves of 76
  int woff2[7];
#pragma unroll
  for (int i = 0; i < 7; ++i) { int e = a + 16 * i; woff2[i] = (e < 100 ? e : 0) * W2_S; }
  float acc2[7];
#pragma unroll
  for (int i = 0; i < 7; ++i) acc2[i] = 0.f;
  const float* hrow = ht + b * HT_S;
  for (int h = 0; h < 2; ++h) {
    __syncthreads();                      // wbuf free / ht ready
    for (int idx = tid; idx < 3800; idx += 64) {      // 100 rows x 38 float2
      int r = idx / 38, c = idx - r * 38;
      int k = 76 * h + 2 * c;
      float2 v;
      if (k < 150) v = *reinterpret_cast<const float2*>(w2 + r * 150 + k);
      else         v = make_float2(0.f, 0.f);
      *reinterpret_cast<float2*>(&wbuf[r * W2_S + 2 * c]) = v;
    }
    __syncthreads();
    const int kb = 76 * h;
#pragma unroll
    for (int k4 = 0; k4 < 19; ++k4) {
      float4 hv = *reinterpret_cast<const float4*>(hrow + kb + 4 * k4);
#pragma unroll
      for (int i = 0; i < 7; ++i) {
        float4 w = *reinterpret_cast<const float4*>(&wbuf[woff2[i] + 4 * k4]);
        acc2[i] += hv.x * w.x; acc2[i] += hv.y * w.y;
        acc2[i] += hv.z * w.z; acc2[i] += hv.w * w.w;
      }
    }
  }
  // LN over the 16 a-lanes (single row per thread)
  float s = 0.f;
#pragma unroll
  for (int i = 0; i < 7; ++i) {
    int e = a + 16 * i;
    if (e < 100) { acc2[i] += b2[e]; s += acc2[i]; }
  }
#pragma unroll
  for (int m = 8; m; m >>= 1) s += __shfl_xor(s, m, 16);
  float mu = s * 0.01f;
  float vv = 0.f;
#pragma unroll
  for (int i = 0; i < 7; ++i) {
    int e = a + 16 * i;
    if (e < 100) { float d = acc2[i] - mu; vv += d * d; }
  }
#pragma unroll
  for (int m = 8; m; m >>= 1) vv += __shfl_xor(vv, m, 16);
  float rs = rsqrtf(vv * 0.01f + 1e-5f);
  if (b < vrows) {
    float* o = out + (row0 + b) * 100;
#pragma unroll
    for (int i = 0; i < 7; ++i) {
      int e = a + 16 * i;
      if (e < 100) o[e] = (acc2[i] - mu) * rs * gg[e] + bb[e];
    }
  }
}

// ---- correl: ht[j][t] = relu(U[i][t]+V[j][t]+b1[t]) then shared phase2 ----
__global__ __launch_bounds__(256, 2) void correl_kernel(
    const float* __restrict__ U, const float* __restrict__ V,
    const float* __restrict__ b1,
    const float* __restrict__ w2, const float* __restrict__ b2,
    const float* __restrict__ gg, const float* __restrict__ bb,
    float* __restrict__ out)
{
  __shared__ __align__(16) float wbuf[WBUF_FLOATS];   // 30.4 KB
  __shared__ __align__(16) float ht[RR * HT_S];       // 39.9 KB
  __shared__ float u_lds[152];
  const int tid = threadIdx.x;
  const int bx = blockIdx.x;           // 4096 = 1024 bi * 4 j-chunks
  const int bi = bx >> 2;              // b*256 + i
  const int j0 = (bx & 3) * RR;
  const int bimg = bi >> 8;
  if (tid < 150) u_lds[tid] = U[(long)bi * 150 + tid] + b1[tid];
  __syncthreads();
  const float2* vb2 = reinterpret_cast<const float2*>(V + ((long)(bimg * 256 + j0)) * 150);
  for (int idx = tid; idx < 4800; idx += 256) {     // 64 rows x 75 float2
    int j = idx / 75, c = idx - j * 75;
    float2 v = vb2[idx];
    ht[j * HT_S + 2 * c]     = fmaxf(u_lds[2 * c]     + v.x, 0.f);
    ht[j * HT_S + 2 * c + 1] = fmaxf(u_lds[2 * c + 1] + v.y, 0.f);
  }
  for (int idx = tid; idx < RR * 6; idx += 256) {   // zero cols 150..155
    int j = idx / 6, c = idx - j * 6;
    ht[j * HT_S + 150 + c] = 0.f;
  }
  phase2_ln(wbuf, ht, RR, w2, b2, gg, bb, out, (long)bi * 256 + j0);
}

// ---- BatchNorm2d stats, two-stage: partial (3ch x 64 slices) + finalize ----
__global__ __launch_bounds__(256) void bn_partial_kernel(
    const float* __restrict__ x, float* __restrict__ part)
{
  __shared__ float s_sum[256], s_sq[256];
  const int c = blockIdx.x >> 6;        // channel
  const int s = blockIdx.x & 63;        // slice within channel
  const int tid = threadIdx.x;
  const int L = s << 12;                // logical start (4096 elems per slice)
  const int b = L >> 16, hw = L & 65535;
  const float4* p4 = reinterpret_cast<const float4*>(
      x + (((long)(b * 3 + c)) << 16) + hw);
  float sum = 0.f, sq = 0.f;
#pragma unroll
  for (int i = 0; i < 4; ++i) {
    float4 v = p4[tid + 256 * i];
    sum += v.x + v.y + v.z + v.w;
    sq += v.x * v.x + v.y * v.y + v.z * v.z + v.w * v.w;
  }
  s_sum[tid] = sum; s_sq[tid] = sq;
  __syncthreads();
  for (int off = 128; off > 0; off >>= 1) {
    if (tid < off) { s_sum[tid] += s_sum[tid + off]; s_sq[tid] += s_sq[tid + off]; }
    __syncthreads();
  }
  if (tid == 0) {
    part[2 * blockIdx.x] = s_sum[0];
    part[2 * blockIdx.x + 1] = s_sq[0];
  }
}

__global__ void bn_finalize_kernel(const float* __restrict__ part,
    const float* __restrict__ bn_w, const float* __restrict__ bn_b,
    float* __restrict__ stats)
{
  const int c = threadIdx.x;
  if (c < 3) {
    float sum = 0.f, sq = 0.f;
    for (int s = 0; s < 64; ++s) {
      sum += part[2 * (c * 64 + s)];
      sq += part[2 * (c * 64 + s) + 1];
    }
    const float n = 262144.f;
    float mu = sum / n;
    float var = sq / n - mu * mu;        // biased var, matches ref
    float rs = rsqrtf(var + 1e-5f);
    float scale = rs * bn_w[c];
    stats[c] = scale;
    stats[4 + c] = bn_b[c] - mu * scale;
  }
}

// ---- patchify + patch-embedding + pos ----
__global__ __launch_bounds__(256) void embed_kernel(
    const float* __restrict__ x, const float* __restrict__ stats,
    const float* __restrict__ pe_w, const float* __restrict__ pe_b,
    const float* __restrict__ pos, float* __restrict__ emb)
{
  __shared__ __align__(16) float patch[768];
  const int tid = threadIdx.x;
  const int bp = blockIdx.x;            // b*256 + p
  const int b = bp >> 8, p = bp & 255;
  const int nhi = p >> 4, nwi = p & 15;
  for (int i = tid; i < 768; i += 256) {
    int ph = i / 48, rem = i % 48;
    int pw = rem / 3, c = rem % 3;
    float v = x[(((long)(b * 3 + c)) * 256 + (nhi * 16 + ph)) * 256 + (nwi * 16 + pw)];
    patch[i] = v * stats[c] + stats[4 + c];
  }
  __syncthreads();
  if (tid < 100) {
    const float* w = pe_w + tid * 768;
    float a0 = 0.f, a1 = 0.f, a2 = 0.f, a3 = 0.f;
    for (int k = 0; k < 768; k += 4) {
      float4 p4 = *reinterpret_cast<const float4*>(patch + k);
      float4 w4 = *reinterpret_cast<const float4*>(w + k);
      a0 += p4.x * w4.x; a1 += p4.y * w4.y;
      a2 += p4.z * w4.z; a3 += p4.w * w4.w;
    }
    emb[(long)bp * 100 + tid] = a0 + a1 + a2 + a3 + pe_b[tid] + pos[p * 100 + tid];
  }
}

// ---- U = W1[:, :100] @ emb, V = W1[:, 100:] @ emb ----
__global__ __launch_bounds__(256) void uv_kernel(
    const float* __restrict__ emb, const float* __restrict__ w1,
    float* __restrict__ U, float* __restrict__ V)
{
  __shared__ __align__(16) float e_lds[100];
  const int tid = threadIdx.x;
  const int bp = blockIdx.x;
  if (tid < 100) e_lds[tid] = emb[(long)bp * 100 + tid];
  __syncthreads();
  if (tid < 150) {
    const float* w = w1 + tid * 200;
    float a0 = 0.f, a1 = 0.f, c0 = 0.f, c1 = 0.f;
    for (int k = 0; k < 100; k += 2) {
      float2 e2 = *reinterpret_cast<const float2*>(e_lds + k);
      a0 += e2.x * w[k];       a1 += e2.y * w[k + 1];
      c0 += e2.x * w[100 + k]; c1 += e2.y * w[100 + k + 1];
    }
    U[(long)bp * 150 + tid] = a0 + a1;
    V[(long)bp * 150 + tid] = c0 + c1;
  }
}

// ---- interleave emb & cc into ec rows of 200 ----
__global__ void ec_kernel(const float* __restrict__ emb,
    const float* __restrict__ cc, float* __restrict__ ec)
{
  int g = blockIdx.x * 256 + threadIdx.x;
  if (g < 1024 * 100) {
    int o = g / 100, e = g % 100;
    ec[(long)o * 200 + 2 * e] = emb[g];
    ec[(long)o * 200 + 2 * e + 1] = cc[g];
  }
}

// ---- final 4-layer MLP head, one block per batch element ----
__global__ __launch_bounds__(256) void head_kernel(
    const float* __restrict__ cp,
    const float* __restrict__ w1, const float* __restrict__ b1,
    const float* __restrict__ w2, const float* __restrict__ b2,
    const float* __restrict__ w3, const float* __restrict__ b3,
    const float* __restrict__ w4, const float* __restrict__ b4,
    float* __restrict__ out)
{
  __shared__ float a0[400], a1[200], a2[100], a3[50];
  const int b = blockIdx.x, tid = threadIdx.x;
  for (int i = tid; i < 400; i += 256) a0[i] = cp[b * 400 + i];
  __syncthreads();
  if (tid < 200) {
    float s = b1[tid];
    const float* w = w1 + tid * 400;
    for (int k = 0; k < 400; ++k) s += a0[k] * w[k];
    a1[tid] = fmaxf(s, 0.f);
  }
  __syncthreads();
  if (tid < 100) {
    float s = b2[tid];
    const float* w = w2 + tid * 200;
    for (int k = 0; k < 200; ++k) s += a1[k] * w[k];
    a2[tid] = fmaxf(s, 0.f);
  }
  __syncthreads();
  if (tid < 50) {
    float s = b3[tid];
    const float* w = w3 + tid * 100;
    for (int k = 0; k < 100; ++k) s += a2[k] * w[k];
    a3[tid] = fmaxf(s, 0.f);
  }
  __syncthreads();
  if (tid < 5) {
    float s = b4[tid];
    const float* w = w4 + tid * 50;
    for (int k = 0; k < 50; ++k) s += a3[k] * w[k];
    out[b * 5 + tid] = s;
  }
}

extern "C" void kernel_launch(void* const* d_in, const int* in_sizes, int n_in,
                              void* d_out, int out_size, void* d_ws, size_t ws_size,
                              hipStream_t stream)
{
  const float* x    = (const float*)d_in[0];
  const float* bn_w = (const float*)d_in[1];
  const float* bn_b = (const float*)d_in[2];
  const float* pe_w = (const float*)d_in[3];
  const float* pe_b = (const float*)d_in[4];
  const float* pos  = (const float*)d_in[5];
  const float* cw1 = (const float*)d_in[6];
  const float* cb1 = (const float*)d_in[7];
  const float* cw2 = (const float*)d_in[8];
  const float* cb2 = (const float*)d_in[9];
  const float* cg  = (const float*)d_in[10];
  const float* cbe = (const float*)d_in[11];
  const float* xw1 = (const float*)d_in[12];
  const float* xb1 = (const float*)d_in[13];
  const float* xw2 = (const float*)d_in[14];
  const float* xb2 = (const float*)d_in[15];
  const float* xg  = (const float*)d_in[16];
  const float* xbe = (const float*)d_in[17];
  const float* aw1 = (const float*)d_in[18];
  const float* ab1 = (const float*)d_in[19];
  const float* aw2 = (const float*)d_in[20];
  const float* ab2 = (const float*)d_in[21];
  const float* ag  = (const float*)d_in[22];
  const float* abe = (const float*)d_in[23];
  const float* pw1 = (const float*)d_in[24];
  const float* pb1 = (const float*)d_in[25];
  const float* pw2 = (const float*)d_in[26];
  const float* pb2 = (const float*)d_in[27];
  const float* pg  = (const float*)d_in[28];
  const float* pbe = (const float*)d_in[29];
  const float* h1w = (const float*)d_in[30];
  const float* h1b = (const float*)d_in[31];
  const float* h2w = (const float*)d_in[32];
  const float* h2b = (const float*)d_in[33];
  const float* h3w = (const float*)d_in[34];
  const float* h3b = (const float*)d_in[35];
  const float* h4w = (const float*)d_in[36];
  const float* h4b = (const float*)d_in[37];

  // workspace layout (floats)
  const size_t OFF_STATS = 0;                       // 16
  const size_t OFF_PART  = 16;                      // 384 (3ch x 64 x {sum,sq})
  const size_t OFF_EMB   = 400;                     // 1024*100
  const size_t OFF_U     = OFF_EMB + 102400;        // 1024*150
  const size_t OFF_V     = OFF_U + 153600;          // 1024*150
  const size_t OFF_EC    = OFF_V + 153600;          // 1024*200
  const size_t OFF_A     = OFF_EC + 204800;         // 262144*100
  const size_t OFF_B     = OFF_A + 26214400;        // 131072*100
  const size_t NEED = (OFF_B + 13107200) * sizeof(float);
  if (ws_size < NEED) return;

  float* ws    = (float*)d_ws;
  float* stats = ws + OFF_STATS;
  float* part  = ws + OFF_PART;
  float* emb   = ws + OFF_EMB;
  float* U     = ws + OFF_U;
  float* V     = ws + OFF_V;
  float* ec    = ws + OFF_EC;
  float* A     = ws + OFF_A;
  float* B     = ws + OFF_B;

  bn_partial_kernel<<<192, 256, 0, stream>>>(x, part);
  bn_finalize_kernel<<<1, 64, 0, stream>>>(part, bn_w, bn_b, stats);
  embed_kernel<<<1024, 256, 0, stream>>>(x, stats, pe_w, pe_b, pos, emb);
  uv_kernel<<<1024, 256, 0, stream>>>(emb, cw1, U, V);
  correl_kernel<<<4096, 256, 0, stream>>>(U, V, cb1, cw2, cb2, cg, cbe, A);

  // xcorr pyramid: d 256 -> 1 (8 merge steps), nrows = output rows
  float* cur = A; float* nxt = B;
  int half = 128;
  for (int s = 0; s < 8; ++s) {
    int nrows = 1024 * half;
    if (nrows > 4096) {
      mlp_merge_kernel<<<(nrows + RR - 1) / RR, 256, 0, stream>>>(
          cur, nxt, xw1, xb1, xw2, xb2, xg, xbe, nrows);
    } else {
      mlp_merge_wave_kernel<<<(nrows + 3) / 4, 64, 0, stream>>>(
          cur, nxt, xw1, xb1, xw2, xb2, xg, xbe, nrows);
    }
    float* t = cur; cur = nxt; nxt = t;
    half >>= 1;
  }
  // cc now in `cur` (== A), 1024 rows of 100

  ec_kernel<<<(102400 + 255) / 256, 256, 0, stream>>>(emb, cur, ec);
  mlp_merge_wave_kernel<<<(1024 + 3) / 4, 64, 0, stream>>>(
      ec, B, aw1, ab1, aw2, ab2, ag, abe, 1024);

  // xpath pyramid: p 256 -> 4 (6 merge steps), nrows = output rows
  cur = B; nxt = A;
  half = 128;
  for (int s = 0; s < 6; ++s) {
    int nrows = 4 * half;
    mlp_merge_wave_kernel<<<(nrows + 3) / 4, 64, 0, stream>>>(
        cur, nxt, pw1, pb1, pw2, pb2, pg, pbe, nrows);
    float* t = cur; cur = nxt; nxt = t;
    half >>= 1;
  }
  // cp now in `cur` (== B), shape (4, 400)

  head_kernel<<<4, 256, 0, stream>>>(cur, h1w, h1b, h2w, h2b, h3w, h3b, h4w, h4b,
                                     (float*)d_out);
}

// Round 15
// 1294.828 us; speedup vs baseline: 1.1362x; 1.1362x over previous
//
#include <hip/hip_runtime.h>

// ---------------------------------------------------------------------------
// BN -> patchify -> embed -> all-pairs MLP_LN (correl, U[i]+V[j] split) ->
// xcorr pyramid -> interleave -> appc -> xpath pyramid -> 4-layer head.
// All fp32.  E=100, HID=150, P=256, B=4.
//
// v18 = v7 (R7 champion, 1295us) byte-for-byte revert.
//  * HT_S 156: ht row-start banks spread (2-way free)
//  * mlp_merge: register-prefetch weight staging; w1 5x40K chunks (W1_S=44),
//    w2 halves 76/76 (W2_S=76)
//  * correl: v5-proven 2-chunk phase-2, no prefetch
// Session ledger: 8 subsequent variants (scalar-w, LDS-uniform, ping-pong,
// 32x8 remap, packed-global-w, 2 tail kernels) all neutral-or-worse; hot
// kernels are LDS-pipe-bound at ~70% VALU (960 LDS-cy : 640 VALU-cy per k4).
// ---------------------------------------------------------------------------

#define RR 64          // rows per block (both kernels)
#define HT_S 156       // ht row stride (156%32=28 -> 8 start banks, 2-way free)
#define W1_S 44        // w1 slab row stride (40-K chunks; 44%32=12 -> 2-way)
#define W2_S 76        // w2 slab row stride (76-K halves; 76%32=12 -> 2-way)
#define WBUF_FLOATS 7600   // max(150*44=6600, 100*76=7600)

// ---- LayerNorm epilogue over acc[7][4] (shared shape) ----
__device__ __forceinline__ void ln_store(
    float acc[7][4], int a, int b, int vrows,
    const float* __restrict__ b2, const float* __restrict__ gg,
    const float* __restrict__ bb, float* __restrict__ out, long row0)
{
  float s[4] = {0.f, 0.f, 0.f, 0.f};
#pragma unroll
  for (int i = 0; i < 7; ++i) {
    int e = a + 16 * i;
    if (e < 100) {
      float bv = b2[e];
#pragma unroll
      for (int j = 0; j < 4; ++j) { acc[i][j] += bv; s[j] += acc[i][j]; }
    }
  }
#pragma unroll
  for (int m = 8; m; m >>= 1)
#pragma unroll
    for (int j = 0; j < 4; ++j) s[j] += __shfl_xor(s[j], m, 16);
  float mu[4], vv[4] = {0.f, 0.f, 0.f, 0.f};
#pragma unroll
  for (int j = 0; j < 4; ++j) mu[j] = s[j] * 0.01f;
#pragma unroll
  for (int i = 0; i < 7; ++i) {
    int e = a + 16 * i;
    if (e < 100) {
#pragma unroll
      for (int j = 0; j < 4; ++j) { float d = acc[i][j] - mu[j]; vv[j] += d * d; }
    }
  }
#pragma unroll
  for (int m = 8; m; m >>= 1)
#pragma unroll
    for (int j = 0; j < 4; ++j) vv[j] += __shfl_xor(vv[j], m, 16);
  float rs[4];
#pragma unroll
  for (int j = 0; j < 4; ++j) rs[j] = rsqrtf(vv[j] * 0.01f + 1e-5f);
#pragma unroll
  for (int j = 0; j < 4; ++j) {
    int r = b + 16 * j;
    if (r < vrows) {
      float* o = out + (row0 + r) * 100;
#pragma unroll
      for (int i = 0; i < 7; ++i) {
        int e = a + 16 * i;
        if (e < 100) o[e] = (acc[i][j] - mu[j]) * rs[j] * gg[e] + bb[e];
      }
    }
  }
}

// ---- phase 2 (v5-style, NO prefetch; used by correl): 2 halves of 76 K ----
__device__ __forceinline__ void phase2_ln_basic(
    float* __restrict__ wbuf, const float* __restrict__ ht, int vrows,
    const float* __restrict__ w2, const float* __restrict__ b2,
    const float* __restrict__ gg, const float* __restrict__ bb,
    float* __restrict__ out, long row0)
{
  const int tid = threadIdx.x;
  const int a = tid & 15;
  const int b = tid >> 4;
  float acc[7][4];
#pragma unroll
  for (int i = 0; i < 7; ++i)
#pragma unroll
    for (int j = 0; j < 4; ++j) acc[i][j] = 0.f;
  int woff[7];
#pragma unroll
  for (int i = 0; i < 7; ++i) { int e = a + 16 * i; woff[i] = (e < 100 ? e : 0) * W2_S; }

  for (int h = 0; h < 2; ++h) {
    __syncthreads();
    for (int idx = tid; idx < 100 * 38; idx += 256) {
      int r = idx / 38, c = idx - r * 38;
      int k = 76 * h + 2 * c;
      float2 v;
      if (k < 150) v = *reinterpret_cast<const float2*>(w2 + r * 150 + k);
      else         v = make_float2(0.f, 0.f);
      *reinterpret_cast<float2*>(&wbuf[r * W2_S + 2 * c]) = v;
    }
    __syncthreads();
    const int kb = 76 * h;
    for (int k4 = 0; k4 < 19; ++k4) {
      float4 hv[4];
#pragma unroll
      for (int j = 0; j < 4; ++j)
        hv[j] = *reinterpret_cast<const float4*>(&ht[(b + 16 * j) * HT_S + kb + 4 * k4]);
#pragma unroll
      for (int i = 0; i < 7; ++i) {
        float4 w = *reinterpret_cast<const float4*>(&wbuf[woff[i] + 4 * k4]);
#pragma unroll
        for (int j = 0; j < 4; ++j) {
          acc[i][j] += hv[j].x * w.x; acc[i][j] += hv[j].y * w.y;
          acc[i][j] += hv[j].z * w.z; acc[i][j] += hv[j].w * w.w;
        }
      }
    }
  }
  ln_store(acc, a, b, vrows, b2, gg, bb, out, row0);
}

// ---- generic merge: rows of 200 -> Linear(150)+ReLU -> Linear(100) -> LN ----
// Register-prefetch staging: chunk c+1 global->regs overlaps compute of c.
__global__ __launch_bounds__(256, 2) void mlp_merge_kernel(
    const float* __restrict__ in, float* __restrict__ out,
    const float* __restrict__ w1, const float* __restrict__ b1,
    const float* __restrict__ w2, const float* __restrict__ b2,
    const float* __restrict__ gg, const float* __restrict__ bb,
    int nrows)
{
  __shared__ __align__(16) float wbuf[WBUF_FLOATS];   // 30.4 KB
  __shared__ __align__(16) float ht[RR * HT_S];       // 39.9 KB
  const int tid = threadIdx.x;
  const int a = tid & 15;
  const int b = tid >> 4;
  const long row0 = (long)blockIdx.x * RR;
  const int vrows = min(RR, (int)(nrows - row0));
  const float* xr[4];
#pragma unroll
  for (int j = 0; j < 4; ++j) {
    int r = b + 16 * j;
    xr[j] = in + (row0 + (r < vrows ? r : 0)) * 200;
  }
  int woff[10];
#pragma unroll
  for (int i = 0; i < 10; ++i) { int t = a + 16 * i; woff[i] = (t < 150 ? t : 0) * W1_S; }
  float acc[10][4];
#pragma unroll
  for (int i = 0; i < 10; ++i)
#pragma unroll
    for (int j = 0; j < 4; ++j) acc[i][j] = 0.f;

  // ---- phase 1: K=200 in 5 chunks of 40 (10 float4 per row) ----
  float4 pf[6];                       // 1500 float4 / 256 threads
#pragma unroll
  for (int i = 0; i < 6; ++i) {       // prefetch chunk 0
    int idx = tid + 256 * i;
    if (idx < 1500) {
      int r = idx / 10, c = idx - r * 10;
      pf[i] = *reinterpret_cast<const float4*>(w1 + r * 200 + 4 * c);
    }
  }
  for (int q = 0; q < 5; ++q) {
    __syncthreads();                  // wbuf free (prev chunk consumed)
#pragma unroll
    for (int i = 0; i < 6; ++i) {
      int idx = tid + 256 * i;
      if (idx < 1500) {
        int r = idx / 10, c = idx - r * 10;
        *reinterpret_cast<float4*>(&wbuf[r * W1_S + 4 * c]) = pf[i];
      }
    }
    __syncthreads();                  // wbuf ready
    if (q < 4) {                      // issue next chunk's loads (hidden under compute)
      const int k0n = 40 * (q + 1);
#pragma unroll
      for (int i = 0; i < 6; ++i) {
        int idx = tid + 256 * i;
        if (idx < 1500) {
          int r = idx / 10, c = idx - r * 10;
          pf[i] = *reinterpret_cast<const float4*>(w1 + r * 200 + k0n + 4 * c);
        }
      }
    }
    const int k0 = 40 * q;
    for (int k4 = 0; k4 < 10; ++k4) {
      float4 xv[4];
#pragma unroll
      for (int j = 0; j < 4; ++j)
        xv[j] = *reinterpret_cast<const float4*>(xr[j] + k0 + 4 * k4);
#pragma unroll
      for (int i = 0; i < 10; ++i) {
        float4 w = *reinterpret_cast<const float4*>(&wbuf[woff[i] + 4 * k4]);
#pragma unroll
        for (int j = 0; j < 4; ++j) {
          acc[i][j] += xv[j].x * w.x; acc[i][j] += xv[j].y * w.y;
          acc[i][j] += xv[j].z * w.z; acc[i][j] += xv[j].w * w.w;
        }
      }
    }
  }

  // prefetch w2 half 0 BEFORE ht writes (loads overlap the LDS writes + barrier)
  float2 pf2[15];                     // 3800 float2 / 256 threads
#pragma unroll
  for (int i = 0; i < 15; ++i) {
    int idx = tid + 256 * i;
    if (idx < 3800) {
      int r = idx / 38, c = idx - r * 38;
      pf2[i] = *reinterpret_cast<const float2*>(w2 + r * 150 + 2 * c);  // k=2c<150
    }
  }
  // ReLU + bias -> ht; zero cols 150..155
#pragma unroll
  for (int i = 0; i < 10; ++i) {
    int t = a + 16 * i;
    if (t < 150) {
      float bt = b1[t];
#pragma unroll
      for (int j = 0; j < 4; ++j)
        ht[(b + 16 * j) * HT_S + t] = fmaxf(acc[i][j] + bt, 0.f);
    } else if (t < 156) {
#pragma unroll
      for (int j = 0; j < 4; ++j)
        ht[(b + 16 * j) * HT_S + t] = 0.f;
    }
  }

  // ---- phase 2: 2 halves of 76 K with prefetch ----
  float acc2[7][4];
#pragma unroll
  for (int i = 0; i < 7; ++i)
#pragma unroll
    for (int j = 0; j < 4; ++j) acc2[i][j] = 0.f;
  int woff2[7];
#pragma unroll
  for (int i = 0; i < 7; ++i) { int e = a + 16 * i; woff2[i] = (e < 100 ? e : 0) * W2_S; }

  for (int h = 0; h < 2; ++h) {
    __syncthreads();                  // h=0: phase1 wbuf consumed & ht written
#pragma unroll
    for (int i = 0; i < 15; ++i) {
      int idx = tid + 256 * i;
      if (idx < 3800) {
        int r = idx / 38, c = idx - r * 38;
        *reinterpret_cast<float2*>(&wbuf[r * W2_S + 2 * c]) = pf2[i];
      }
    }
    __syncthreads();
    if (h == 0) {                     // prefetch half 1 (k = 76+2c; zero k>=150)
#pragma unroll
      for (int i = 0; i < 15; ++i) {
        int idx = tid + 256 * i;
        if (idx < 3800) {
          int r = idx / 38, c = idx - r * 38;
          int k = 76 + 2 * c;
          if (k < 150) pf2[i] = *reinterpret_cast<const float2*>(w2 + r * 150 + k);
          else         pf2[i] = make_float2(0.f, 0.f);
        }
      }
    }
    const int kb = 76 * h;
    for (int k4 = 0; k4 < 19; ++k4) {
      float4 hv[4];
#pragma unroll
      for (int j = 0; j < 4; ++j)
        hv[j] = *reinterpret_cast<const float4*>(&ht[(b + 16 * j) * HT_S + kb + 4 * k4]);
#pragma unroll
      for (int i = 0; i < 7; ++i) {
        float4 w = *reinterpret_cast<const float4*>(&wbuf[woff2[i] + 4 * k4]);
#pragma unroll
        for (int j = 0; j < 4; ++j) {
          acc2[i][j] += hv[j].x * w.x; acc2[i][j] += hv[j].y * w.y;
          acc2[i][j] += hv[j].z * w.z; acc2[i][j] += hv[j].w * w.w;
        }
      }
    }
  }
  ln_store(acc2, a, b, vrows, b2, gg, bb, out, row0);
}

// ---- correl: ht[j][t] = relu(U[i][t]+V[j][t]+b1[t]) then v5 phase2+LN ----
__global__ __launch_bounds__(256, 2) void correl_kernel(
    const float* __restrict__ U, const float* __restrict__ V,
    const float* __restrict__ b1,
    const float* __restrict__ w2, const float* __restrict__ b2,
    const float* __restrict__ gg, const float* __restrict__ bb,
    float* __restrict__ out)
{
  __shared__ __align__(16) float wbuf[WBUF_FLOATS];   // 30.4 KB
  __shared__ __align__(16) float ht[RR * HT_S];       // 39.9 KB
  __shared__ float u_lds[152];
  const int tid = threadIdx.x;
  const int bx = blockIdx.x;           // 4096 = 1024 bi * 4 j-chunks
  const int bi = bx >> 2;              // b*256 + i
  const int j0 = (bx & 3) * RR;
  const int bimg = bi >> 8;
  if (tid < 150) u_lds[tid] = U[(long)bi * 150 + tid] + b1[tid];
  __syncthreads();
  const float2* vb2 = reinterpret_cast<const float2*>(V + ((long)(bimg * 256 + j0)) * 150);
  for (int idx = tid; idx < 4800; idx += 256) {     // 64 rows x 75 float2
    int j = idx / 75, c = idx - j * 75;
    float2 v = vb2[idx];
    ht[j * HT_S + 2 * c]     = fmaxf(u_lds[2 * c]     + v.x, 0.f);
    ht[j * HT_S + 2 * c + 1] = fmaxf(u_lds[2 * c + 1] + v.y, 0.f);
  }
  for (int idx = tid; idx < RR * 6; idx += 256) {   // zero cols 150..155
    int j = idx / 6, c = idx - j * 6;
    ht[j * HT_S + 150 + c] = 0.f;
  }
  phase2_ln_basic(wbuf, ht, RR, w2, b2, gg, bb, out, (long)bi * 256 + j0);
}

// ---- BatchNorm2d stats, two-stage: partial (3ch x 64 slices) + finalize ----
__global__ __launch_bounds__(256) void bn_partial_kernel(
    const float* __restrict__ x, float* __restrict__ part)
{
  __shared__ float s_sum[256], s_sq[256];
  const int c = blockIdx.x >> 6;        // channel
  const int s = blockIdx.x & 63;        // slice within channel
  const int tid = threadIdx.x;
  const int L = s << 12;                // logical start (4096 elems per slice)
  const int b = L >> 16, hw = L & 65535;
  const float4* p4 = reinterpret_cast<const float4*>(
      x + (((long)(b * 3 + c)) << 16) + hw);
  float sum = 0.f, sq = 0.f;
#pragma unroll
  for (int i = 0; i < 4; ++i) {
    float4 v = p4[tid + 256 * i];
    sum += v.x + v.y + v.z + v.w;
    sq += v.x * v.x + v.y * v.y + v.z * v.z + v.w * v.w;
  }
  s_sum[tid] = sum; s_sq[tid] = sq;
  __syncthreads();
  for (int off = 128; off > 0; off >>= 1) {
    if (tid < off) { s_sum[tid] += s_sum[tid + off]; s_sq[tid] += s_sq[tid + off]; }
    __syncthreads();
  }
  if (tid == 0) {
    part[2 * blockIdx.x] = s_sum[0];
    part[2 * blockIdx.x + 1] = s_sq[0];
  }
}

__global__ void bn_finalize_kernel(const float* __restrict__ part,
    const float* __restrict__ bn_w, const float* __restrict__ bn_b,
    float* __restrict__ stats)
{
  const int c = threadIdx.x;
  if (c < 3) {
    float sum = 0.f, sq = 0.f;
    for (int s = 0; s < 64; ++s) {
      sum += part[2 * (c * 64 + s)];
      sq += part[2 * (c * 64 + s) + 1];
    }
    const float n = 262144.f;
    float mu = sum / n;
    float var = sq / n - mu * mu;        // biased var, matches ref
    float rs = rsqrtf(var + 1e-5f);
    float scale = rs * bn_w[c];
    stats[c] = scale;
    stats[4 + c] = bn_b[c] - mu * scale;
  }
}

// ---- patchify + patch-embedding + pos ----
__global__ __launch_bounds__(256) void embed_kernel(
    const float* __restrict__ x, const float* __restrict__ stats,
    const float* __restrict__ pe_w, const float* __restrict__ pe_b,
    const float* __restrict__ pos, float* __restrict__ emb)
{
  __shared__ __align__(16) float patch[768];
  const int tid = threadIdx.x;
  const int bp = blockIdx.x;            // b*256 + p
  const int b = bp >> 8, p = bp & 255;
  const int nhi = p >> 4, nwi = p & 15;
  for (int i = tid; i < 768; i += 256) {
    int ph = i / 48, rem = i % 48;
    int pw = rem / 3, c = rem % 3;
    float v = x[(((long)(b * 3 + c)) * 256 + (nhi * 16 + ph)) * 256 + (nwi * 16 + pw)];
    patch[i] = v * stats[c] + stats[4 + c];
  }
  __syncthreads();
  if (tid < 100) {
    const float* w = pe_w + tid * 768;
    float a0 = 0.f, a1 = 0.f, a2 = 0.f, a3 = 0.f;
    for (int k = 0; k < 768; k += 4) {
      float4 p4 = *reinterpret_cast<const float4*>(patch + k);
      float4 w4 = *reinterpret_cast<const float4*>(w + k);
      a0 += p4.x * w4.x; a1 += p4.y * w4.y;
      a2 += p4.z * w4.z; a3 += p4.w * w4.w;
    }
    emb[(long)bp * 100 + tid] = a0 + a1 + a2 + a3 + pe_b[tid] + pos[p * 100 + tid];
  }
}

// ---- U = W1[:, :100] @ emb, V = W1[:, 100:] @ emb ----
__global__ __launch_bounds__(256) void uv_kernel(
    const float* __restrict__ emb, const float* __restrict__ w1,
    float* __restrict__ U, float* __restrict__ V)
{
  __shared__ __align__(16) float e_lds[100];
  const int tid = threadIdx.x;
  const int bp = blockIdx.x;
  if (tid < 100) e_lds[tid] = emb[(long)bp * 100 + tid];
  __syncthreads();
  if (tid < 150) {
    const float* w = w1 + tid * 200;
    float a0 = 0.f, a1 = 0.f, c0 = 0.f, c1 = 0.f;
    for (int k = 0; k < 100; k += 2) {
      float2 e2 = *reinterpret_cast<const float2*>(e_lds + k);
      a0 += e2.x * w[k];       a1 += e2.y * w[k + 1];
      c0 += e2.x * w[100 + k]; c1 += e2.y * w[100 + k + 1];
    }
    U[(long)bp * 150 + tid] = a0 + a1;
    V[(long)bp * 150 + tid] = c0 + c1;
  }
}

// ---- interleave emb & cc into ec rows of 200 ----
__global__ void ec_kernel(const float* __restrict__ emb,
    const float* __restrict__ cc, float* __restrict__ ec)
{
  int g = blockIdx.x * 256 + threadIdx.x;
  if (g < 1024 * 100) {
    int o = g / 100, e = g % 100;
    ec[(long)o * 200 + 2 * e] = emb[g];
    ec[(long)o * 200 + 2 * e + 1] = cc[g];
  }
}

// ---- final 4-layer MLP head, one block per batch element ----
__global__ __launch_bounds__(256) void head_kernel(
    const float* __restrict__ cp,
    const float* __restrict__ w1, const float* __restrict__ b1,
    const float* __restrict__ w2, const float* __restrict__ b2,
    const float* __restrict__ w3, const float* __restrict__ b3,
    const float* __restrict__ w4, const float* __restrict__ b4,
    float* __restrict__ out)
{
  __shared__ float a0[400], a1[200], a2[100], a3[50];
  const int b = blockIdx.x, tid = threadIdx.x;
  for (int i = tid; i < 400; i += 256) a0[i] = cp[b * 400 + i];
  __syncthreads();
  if (tid < 200) {
    float s = b1[tid];
    const float* w = w1 + tid * 400;
    for (int k = 0; k < 400; ++k) s += a0[k] * w[k];
    a1[tid] = fmaxf(s, 0.f);
  }
  __syncthreads();
  if (tid < 100) {
    float s = b2[tid];
    const float* w = w2 + tid * 200;
    for (int k = 0; k < 200; ++k) s += a1[k] * w[k];
    a2[tid] = fmaxf(s, 0.f);
  }
  __syncthreads();
  if (tid < 50) {
    float s = b3[tid];
    const float* w = w3 + tid * 100;
    for (int k = 0; k < 100; ++k) s += a2[k] * w[k];
    a3[tid] = fmaxf(s, 0.f);
  }
  __syncthreads();
  if (tid < 5) {
    float s = b4[tid];
    const float* w = w4 + tid * 50;
    for (int k = 0; k < 50; ++k) s += a3[k] * w[k];
    out[b * 5 + tid] = s;
  }
}

extern "C" void kernel_launch(void* const* d_in, const int* in_sizes, int n_in,
                              void* d_out, int out_size, void* d_ws, size_t ws_size,
                              hipStream_t stream)
{
  const float* x    = (const float*)d_in[0];
  const float* bn_w = (const float*)d_in[1];
  const float* bn_b = (const float*)d_in[2];
  const float* pe_w = (const float*)d_in[3];
  const float* pe_b = (const float*)d_in[4];
  const float* pos  = (const float*)d_in[5];
  const float* cw1 = (const float*)d_in[6];
  const float* cb1 = (const float*)d_in[7];
  const float* cw2 = (const float*)d_in[8];
  const float* cb2 = (const float*)d_in[9];
  const float* cg  = (const float*)d_in[10];
  const float* cbe = (const float*)d_in[11];
  const float* xw1 = (const float*)d_in[12];
  const float* xb1 = (const float*)d_in[13];
  const float* xw2 = (const float*)d_in[14];
  const float* xb2 = (const float*)d_in[15];
  const float* xg  = (const float*)d_in[16];
  const float* xbe = (const float*)d_in[17];
  const float* aw1 = (const float*)d_in[18];
  const float* ab1 = (const float*)d_in[19];
  const float* aw2 = (const float*)d_in[20];
  const float* ab2 = (const float*)d_in[21];
  const float* ag  = (const float*)d_in[22];
  const float* abe = (const float*)d_in[23];
  const float* pw1 = (const float*)d_in[24];
  const float* pb1 = (const float*)d_in[25];
  const float* pw2 = (const float*)d_in[26];
  const float* pb2 = (const float*)d_in[27];
  const float* pg  = (const float*)d_in[28];
  const float* pbe = (const float*)d_in[29];
  const float* h1w = (const float*)d_in[30];
  const float* h1b = (const float*)d_in[31];
  const float* h2w = (const float*)d_in[32];
  const float* h2b = (const float*)d_in[33];
  const float* h3w = (const float*)d_in[34];
  const float* h3b = (const float*)d_in[35];
  const float* h4w = (const float*)d_in[36];
  const float* h4b = (const float*)d_in[37];

  // workspace layout (floats)
  const size_t OFF_STATS = 0;                       // 16
  const size_t OFF_PART  = 16;                      // 384 (3ch x 64 x {sum,sq})
  const size_t OFF_EMB   = 400;                     // 1024*100
  const size_t OFF_U     = OFF_EMB + 102400;        // 1024*150
  const size_t OFF_V     = OFF_U + 153600;          // 1024*150
  const size_t OFF_EC    = OFF_V + 153600;          // 1024*200
  const size_t OFF_A     = OFF_EC + 204800;         // 262144*100
  const size_t OFF_B     = OFF_A + 26214400;        // 131072*100
  const size_t NEED = (OFF_B + 13107200) * sizeof(float);
  if (ws_size < NEED) return;

  float* ws    = (float*)d_ws;
  float* stats = ws + OFF_STATS;
  float* part  = ws + OFF_PART;
  float* emb   = ws + OFF_EMB;
  float* U     = ws + OFF_U;
  float* V     = ws + OFF_V;
  float* ec    = ws + OFF_EC;
  float* A     = ws + OFF_A;
  float* B     = ws + OFF_B;

  bn_partial_kernel<<<192, 256, 0, stream>>>(x, part);
  bn_finalize_kernel<<<1, 64, 0, stream>>>(part, bn_w, bn_b, stats);
  embed_kernel<<<1024, 256, 0, stream>>>(x, stats, pe_w, pe_b, pos, emb);
  uv_kernel<<<1024, 256, 0, stream>>>(emb, cw1, U, V);
  correl_kernel<<<4096, 256, 0, stream>>>(U, V, cb1, cw2, cb2, cg, cbe, A);

  // xcorr pyramid: d 256 -> 1 (8 merge steps), rows = 1024 * half
  float* cur = A; float* nxt = B;
  int half = 128;
  for (int s = 0; s < 8; ++s) {
    int nrows = 1024 * half;
    mlp_merge_kernel<<<(nrows + RR - 1) / RR, 256, 0, stream>>>(
        cur, nxt, xw1, xb1, xw2, xb2, xg, xbe, nrows);
    float* t = cur; cur = nxt; nxt = t;
    half >>= 1;
  }
  // cc now in `cur` (== A), 1024 rows of 100

  ec_kernel<<<(102400 + 255) / 256, 256, 0, stream>>>(emb, cur, ec);
  mlp_merge_kernel<<<(1024 + RR - 1) / RR, 256, 0, stream>>>(
      ec, B, aw1, ab1, aw2, ab2, ag, abe, 1024);

  // xpath pyramid: p 256 -> 4 (6 merge steps), rows = 4 * half
  cur = B; nxt = A;
  half = 128;
  for (int s = 0; s < 6; ++s) {
    int nrows = 4 * half;
    mlp_merge_kernel<<<(nrows + RR - 1) / RR, 256, 0, stream>>>(
        cur, nxt, pw1, pb1, pw2, pb2, pg, pbe, nrows);
    float* t = cur; cur = nxt; nxt = t;
    half >>= 1;
  }
  // cp now in `cur` (== B), shape (4, 400)

  head_kernel<<<4, 256, 0, stream>>>(cur, h1w, h1b, h2w, h2b, h3w, h3b, h4w, h4b,
                                     (float*)d_out);
}